// Round 1
// baseline (667.518 us; speedup 1.0000x reference)
//
#include <hip/hip_runtime.h>

// Problem constants (from reference)
#define N_NODES  50000
#define N_EDGES  1600000
#define NODE_DIM 1024
#define HID      128
#define LN_EPS   1e-5f
#define PAD_NODES 50176   // 196*256, scan-friendly padding

typedef float f32x4 __attribute__((ext_vector_type(4)));
typedef __bf16 bf16x8 __attribute__((ext_vector_type(8)));
typedef unsigned short u16x8 __attribute__((ext_vector_type(8)));

__device__ __forceinline__ unsigned short f2bf(float f) {
  unsigned int u = __float_as_uint(f);
  u += 0x7fffu + ((u >> 16) & 1u);   // round-to-nearest-even
  return (unsigned short)(u >> 16);
}

__device__ __forceinline__ void pack16(const float4 v0, const float4 v1,
                                       const float4 v2, const float4 v3,
                                       unsigned short* dst) {
  u16x8 p0 = {f2bf(v0.x), f2bf(v0.y), f2bf(v0.z), f2bf(v0.w),
              f2bf(v1.x), f2bf(v1.y), f2bf(v1.z), f2bf(v1.w)};
  u16x8 p1 = {f2bf(v2.x), f2bf(v2.y), f2bf(v2.z), f2bf(v2.w),
              f2bf(v3.x), f2bf(v3.y), f2bf(v3.z), f2bf(v3.w)};
  *(u16x8*)(dst)     = p0;
  *(u16x8*)(dst + 8) = p1;
}

// ---------------------------------------------------------------------------
// K0: zero deg + accum (ws is poisoned 0xAA before every call)
// ---------------------------------------------------------------------------
__global__ __launch_bounds__(256) void k_zero(int* __restrict__ deg,
                                              float* __restrict__ accum) {
  int i = blockIdx.x * 256 + threadIdx.x;
  if (i < PAD_NODES) deg[i] = 0;
  if (i < HID) accum[i] = 0.f;
}

// ---------------------------------------------------------------------------
// K1: h = relu(x @ proj_w^T + proj_b)   [50000,1024] x [128,1024]^T
// 128x128 tile / block, 4 waves, each wave a 64x64 quadrant of 16x16x32 MFMAs
// ---------------------------------------------------------------------------
__global__ __launch_bounds__(256) void k_proj(const float* __restrict__ x,
                                              const float* __restrict__ pw,
                                              const float* __restrict__ pb,
                                              float* __restrict__ h) {
  __shared__ unsigned short As[128 * 32];
  __shared__ unsigned short Bs[128 * 32];
  const int tid  = threadIdx.x;
  const int m0   = blockIdx.x * 128;
  const int wave = tid >> 6, lane = tid & 63;
  const int wm = (wave >> 1) * 64, wn = (wave & 1) * 64;
  const int srow = tid >> 1;
  const int scol = (tid & 1) * 16;
  const int fr = lane & 15, ko = (lane >> 4) * 8;

  f32x4 acc[4][4];
#pragma unroll
  for (int m = 0; m < 4; m++)
#pragma unroll
    for (int n = 0; n < 4; n++) acc[m][n] = (f32x4){0.f, 0.f, 0.f, 0.f};

  for (int k0 = 0; k0 < NODE_DIM; k0 += 32) {
    const int arow = m0 + srow;
    float4 a0, a1, a2, a3;
    if (arow < N_NODES) {
      const float4* p = (const float4*)(x + (size_t)arow * NODE_DIM + k0 + scol);
      a0 = p[0]; a1 = p[1]; a2 = p[2]; a3 = p[3];
    } else {
      a0 = a1 = a2 = a3 = make_float4(0.f, 0.f, 0.f, 0.f);
    }
    const float4* q = (const float4*)(pw + (size_t)srow * NODE_DIM + k0 + scol);
    float4 b0 = q[0], b1 = q[1], b2 = q[2], b3 = q[3];

    __syncthreads();
    pack16(a0, a1, a2, a3, &As[srow * 32 + scol]);
    pack16(b0, b1, b2, b3, &Bs[srow * 32 + scol]);
    __syncthreads();

    bf16x8 af[4], bfr[4];
#pragma unroll
    for (int m = 0; m < 4; m++)
      af[m] = *(const bf16x8*)&As[(wm + m * 16 + fr) * 32 + ko];
#pragma unroll
    for (int n = 0; n < 4; n++)
      bfr[n] = *(const bf16x8*)&Bs[(wn + n * 16 + fr) * 32 + ko];
#pragma unroll
    for (int m = 0; m < 4; m++)
#pragma unroll
      for (int n = 0; n < 4; n++)
        acc[m][n] = __builtin_amdgcn_mfma_f32_16x16x32_bf16(af[m], bfr[n], acc[m][n], 0, 0, 0);
  }

  const int cr = (lane >> 4) * 4, cc = lane & 15;
#pragma unroll
  for (int n = 0; n < 4; n++) {
    const int col = wn + n * 16 + cc;
    const float bias = pb[col];
#pragma unroll
    for (int m = 0; m < 4; m++) {
#pragma unroll
      for (int i = 0; i < 4; i++) {
        const int row = m0 + wm + m * 16 + cr + i;
        if (row < N_NODES) {
          float v = acc[m][n][i] + bias;
          h[(size_t)row * HID + col] = v > 0.f ? v : 0.f;
        }
      }
    }
  }
}

// ---------------------------------------------------------------------------
// K2: CSR build — count, scan (3 stages), fill
// ---------------------------------------------------------------------------
__global__ __launch_bounds__(256) void k_count(const int* __restrict__ ei,
                                               int* __restrict__ deg) {
  int e = blockIdx.x * 256 + threadIdx.x;
  if (e < N_EDGES) atomicAdd(&deg[ei[N_EDGES + e]], 1);
}

__global__ __launch_bounds__(256) void k_scanA(const int* __restrict__ deg,
                                               int* __restrict__ bsum) {
  __shared__ int sd[256];
  int t = threadIdx.x;
  int i = blockIdx.x * 256 + t;
  sd[t] = (i < PAD_NODES) ? deg[i] : 0;
  __syncthreads();
  for (int s = 128; s > 0; s >>= 1) {
    if (t < s) sd[t] += sd[t + s];
    __syncthreads();
  }
  if (t == 0) bsum[blockIdx.x] = sd[0];
}

__global__ __launch_bounds__(256) void k_scanB(const int* __restrict__ bsum,
                                               int* __restrict__ boff) {
  __shared__ int buf[2][256];
  int t = threadIdx.x;
  int v = (t < 196) ? bsum[t] : 0;
  int cur = 0;
  buf[0][t] = v;
  __syncthreads();
  for (int off = 1; off < 256; off <<= 1) {
    int nxt = cur ^ 1;
    int s = buf[cur][t];
    if (t >= off) s += buf[cur][t - off];
    buf[nxt][t] = s;
    cur = nxt;
    __syncthreads();
  }
  boff[t] = buf[cur][t] - v;   // exclusive
}

__global__ __launch_bounds__(256) void k_scanC(const int* __restrict__ deg,
                                               const int* __restrict__ boff,
                                               int* __restrict__ offs,
                                               int* __restrict__ curs) {
  __shared__ int buf[2][256];
  int t = threadIdx.x;
  int i = blockIdx.x * 256 + t;
  int v = (i < PAD_NODES) ? deg[i] : 0;
  int cur = 0;
  buf[0][t] = v;
  __syncthreads();
  for (int off = 1; off < 256; off <<= 1) {
    int nxt = cur ^ 1;
    int s = buf[cur][t];
    if (t >= off) s += buf[cur][t - off];
    buf[nxt][t] = s;
    cur = nxt;
    __syncthreads();
  }
  int o = boff[blockIdx.x] + buf[cur][t] - v;
  if (i < PAD_NODES) { offs[i] = o; curs[i] = o; }
}

__global__ __launch_bounds__(256) void k_fill(const int* __restrict__ ei,
                                              int* __restrict__ curs,
                                              int* __restrict__ nbr) {
  int e = blockIdx.x * 256 + threadIdx.x;
  if (e < N_EDGES) {
    int d = ei[N_EDGES + e];
    int s = ei[e];
    int slot = atomicAdd(&curs[d], 1);
    nbr[slot] = s;
  }
}

// ---------------------------------------------------------------------------
// K3: gather + mean.  One wave per node; half-wave per neighbor parity.
// lanes 0-31 = even neighbors, 32-63 = odd; each li covers 4 floats (float4).
// ---------------------------------------------------------------------------
__global__ __launch_bounds__(256) void k_gather(const float* __restrict__ h,
                                                const int* __restrict__ nbr,
                                                const int* __restrict__ offs,
                                                const int* __restrict__ deg,
                                                float* __restrict__ mn) {
  const int wave = threadIdx.x >> 6;
  const int lane = threadIdx.x & 63;
  const int node = blockIdx.x * 4 + wave;
  if (node >= N_NODES) return;
  const int li = lane & 31, half = lane >> 5;
  const int d  = deg[node];
  const int st = offs[node];
  float ax = 0.f, ay = 0.f, az = 0.f, aw = 0.f;
  const float4* h4 = (const float4*)h;
  for (int n = half; n < d; n += 2) {
    int s = nbr[st + n];
    float4 v = h4[(size_t)s * 32 + li];
    ax += v.x; ay += v.y; az += v.z; aw += v.w;
  }
  ax += __shfl_xor(ax, 32);
  ay += __shfl_xor(ay, 32);
  az += __shfl_xor(az, 32);
  aw += __shfl_xor(aw, 32);
  if (half == 0) {
    float inv = 1.f / fmaxf((float)d, 1.f);
    float4 r = make_float4(ax * inv, ay * inv, az * inv, aw * inv);
    ((float4*)mn)[(size_t)node * 32 + li] = r;
  }
}

// ---------------------------------------------------------------------------
// K4: h2 = [mn | h] @ [lin_l_w | lin_r_w]^T + lin_l_b  (K=256, bf16 MFMA)
// h2 written IN PLACE over mn (safe: each block reads only its own 128 rows,
// entirely before its epilogue; row tiles are disjoint across blocks).
// ---------------------------------------------------------------------------
__global__ __launch_bounds__(256) void k_sage(float* mn,                 // in: mean_nbr, out: h2
                                              const float* __restrict__ h,
                                              const float* __restrict__ wl,
                                              const float* __restrict__ wr,
                                              const float* __restrict__ lb) {
  __shared__ unsigned short As[128 * 32];
  __shared__ unsigned short Bs[128 * 32];
  const int tid  = threadIdx.x;
  const int m0   = blockIdx.x * 128;
  const int wave = tid >> 6, lane = tid & 63;
  const int wm = (wave >> 1) * 64, wn = (wave & 1) * 64;
  const int srow = tid >> 1;
  const int scol = (tid & 1) * 16;
  const int fr = lane & 15, ko = (lane >> 4) * 8;

  f32x4 acc[4][4];
#pragma unroll
  for (int m = 0; m < 4; m++)
#pragma unroll
    for (int n = 0; n < 4; n++) acc[m][n] = (f32x4){0.f, 0.f, 0.f, 0.f};

  for (int k0 = 0; k0 < 2 * HID; k0 += 32) {
    const float* baseA = (k0 < HID) ? (const float*)mn : h;
    const float* baseB = (k0 < HID) ? wl : wr;
    const int kk = (k0 & (HID - 1)) + scol;
    const int arow = m0 + srow;
    float4 a0, a1, a2, a3;
    if (arow < N_NODES) {
      const float4* p = (const float4*)(baseA + (size_t)arow * HID + kk);
      a0 = p[0]; a1 = p[1]; a2 = p[2]; a3 = p[3];
    } else {
      a0 = a1 = a2 = a3 = make_float4(0.f, 0.f, 0.f, 0.f);
    }
    const float4* q = (const float4*)(baseB + (size_t)srow * HID + kk);
    float4 b0 = q[0], b1 = q[1], b2 = q[2], b3 = q[3];

    __syncthreads();
    pack16(a0, a1, a2, a3, &As[srow * 32 + scol]);
    pack16(b0, b1, b2, b3, &Bs[srow * 32 + scol]);
    __syncthreads();

    bf16x8 af[4], bfr[4];
#pragma unroll
    for (int m = 0; m < 4; m++)
      af[m] = *(const bf16x8*)&As[(wm + m * 16 + fr) * 32 + ko];
#pragma unroll
    for (int n = 0; n < 4; n++)
      bfr[n] = *(const bf16x8*)&Bs[(wn + n * 16 + fr) * 32 + ko];
#pragma unroll
    for (int m = 0; m < 4; m++)
#pragma unroll
      for (int n = 0; n < 4; n++)
        acc[m][n] = __builtin_amdgcn_mfma_f32_16x16x32_bf16(af[m], bfr[n], acc[m][n], 0, 0, 0);
  }

  const int cr = (lane >> 4) * 4, cc = lane & 15;
#pragma unroll
  for (int n = 0; n < 4; n++) {
    const int col = wn + n * 16 + cc;
    const float bias = lb[col];
#pragma unroll
    for (int m = 0; m < 4; m++) {
#pragma unroll
      for (int i = 0; i < 4; i++) {
        const int row = m0 + wm + m * 16 + cr + i;
        if (row < N_NODES)
          mn[(size_t)row * HID + col] = acc[m][n][i] + bias;
      }
    }
  }
}

// ---------------------------------------------------------------------------
// K5: LayerNorm + ReLU + global mean-pool partials.
// 1024 waves; each wave owns nodes w, w+1024, ...; lane covers feats (l, l+64)
// ---------------------------------------------------------------------------
__global__ __launch_bounds__(256) void k_ln_pool(const float* __restrict__ h2,
                                                 const float* __restrict__ lg,
                                                 const float* __restrict__ lbt,
                                                 float* __restrict__ accum) {
  const int wave = threadIdx.x >> 6;
  const int lane = threadIdx.x & 63;
  const int w = blockIdx.x * 4 + wave;
  const float g0 = lg[lane], g1 = lg[lane + 64];
  const float t0 = lbt[lane], t1 = lbt[lane + 64];
  float accx = 0.f, accy = 0.f;
  for (int i = w; i < N_NODES; i += 1024) {
    float v0 = h2[(size_t)i * HID + lane];
    float v1 = h2[(size_t)i * HID + lane + 64];
    float s = v0 + v1, ss = v0 * v0 + v1 * v1;
#pragma unroll
    for (int off = 32; off > 0; off >>= 1) {
      s  += __shfl_xor(s, off);
      ss += __shfl_xor(ss, off);
    }
    float mu  = s * (1.f / HID);
    float var = ss * (1.f / HID) - mu * mu;
    float r = rsqrtf(var + LN_EPS);
    float y0 = (v0 - mu) * r * g0 + t0;
    float y1 = (v1 - mu) * r * g1 + t1;
    accx += (y0 > 0.f ? y0 : 0.f);
    accy += (y1 > 0.f ? y1 : 0.f);
  }
  __shared__ float red[4][128];
  red[wave][lane] = accx;
  red[wave][lane + 64] = accy;
  __syncthreads();
  if (wave == 0) {
    float a = red[0][lane] + red[1][lane] + red[2][lane] + red[3][lane];
    float b = red[0][lane + 64] + red[1][lane + 64] + red[2][lane + 64] + red[3][lane + 64];
    atomicAdd(&accum[lane], a);
    atomicAdd(&accum[lane + 64], b);
  }
}

// ---------------------------------------------------------------------------
// K6: out = (accum/N) @ out_w^T + out_b    (single block)
// ---------------------------------------------------------------------------
__global__ __launch_bounds__(128) void k_final(const float* __restrict__ accum,
                                               const float* __restrict__ ow,
                                               const float* __restrict__ ob,
                                               float* __restrict__ out) {
  __shared__ float gs[HID];
  int t = threadIdx.x;
  gs[t] = accum[t] * (1.f / N_NODES);
  __syncthreads();
  float s = ob[t];
  for (int k = 0; k < HID; k++) s += gs[k] * ow[t * HID + k];
  out[t] = s;
}

// ---------------------------------------------------------------------------
extern "C" void kernel_launch(void* const* d_in, const int* in_sizes, int n_in,
                              void* d_out, int out_size, void* d_ws, size_t ws_size,
                              hipStream_t stream) {
  const float* x   = (const float*)d_in[0];
  const int*   ei  = (const int*)d_in[1];
  const float* pw  = (const float*)d_in[2];
  const float* pb  = (const float*)d_in[3];
  const float* wl  = (const float*)d_in[4];
  const float* lb  = (const float*)d_in[5];
  const float* wr  = (const float*)d_in[6];
  const float* lg  = (const float*)d_in[7];
  const float* lbt = (const float*)d_in[8];
  const float* ow  = (const float*)d_in[9];
  const float* ob  = (const float*)d_in[10];
  float* out = (float*)d_out;

  // workspace carve (~58.3 MB): h | mn(=h2) | nbr | deg | offs | curs | bsum | boff | accum
  float* h  = (float*)d_ws;
  float* mn = h + (size_t)PAD_NODES * HID;
  int* nbr  = (int*)(mn + (size_t)PAD_NODES * HID);
  int* deg  = nbr + N_EDGES;
  int* offs = deg + PAD_NODES;
  int* curs = offs + PAD_NODES;
  int* bsum = curs + PAD_NODES;
  int* boff = bsum + 256;
  float* accum = (float*)(boff + 256);

  const int MB = (N_NODES + 127) / 128;          // 391
  const int EB = (N_EDGES + 255) / 256;          // 6250

  hipLaunchKernelGGL(k_zero,   dim3(PAD_NODES / 256), dim3(256), 0, stream, deg, accum);
  hipLaunchKernelGGL(k_proj,   dim3(MB),  dim3(256), 0, stream, x, pw, pb, h);
  hipLaunchKernelGGL(k_count,  dim3(EB),  dim3(256), 0, stream, ei, deg);
  hipLaunchKernelGGL(k_scanA,  dim3(196), dim3(256), 0, stream, deg, bsum);
  hipLaunchKernelGGL(k_scanB,  dim3(1),   dim3(256), 0, stream, bsum, boff);
  hipLaunchKernelGGL(k_scanC,  dim3(196), dim3(256), 0, stream, deg, boff, offs, curs);
  hipLaunchKernelGGL(k_fill,   dim3(EB),  dim3(256), 0, stream, ei, curs, nbr);
  hipLaunchKernelGGL(k_gather, dim3((N_NODES + 3) / 4), dim3(256), 0, stream, h, nbr, offs, deg, mn);
  hipLaunchKernelGGL(k_sage,   dim3(MB),  dim3(256), 0, stream, mn, h, wl, wr, lb);
  hipLaunchKernelGGL(k_ln_pool,dim3(256), dim3(256), 0, stream, mn, lg, lbt, accum);
  hipLaunchKernelGGL(k_final,  dim3(1),   dim3(128), 0, stream, accum, ow, ob, out);
}

// Round 2
// 506.669 us; speedup vs baseline: 1.3175x; 1.3175x over previous
//
#include <hip/hip_runtime.h>

// Problem constants
#define N_NODES  50000
#define N_EDGES  1600000
#define NODE_DIM 1024
#define HID      128
#define LN_EPS   1e-5f
#define PAD_NODES 50176           // 196*256
#define NBUCK    196              // dst>>8 buckets (256 nodes each)
#define SHARD    6250             // N_EDGES / 256

typedef float f32x4 __attribute__((ext_vector_type(4)));
typedef __bf16 bf16x8 __attribute__((ext_vector_type(8)));
typedef unsigned short u16x8 __attribute__((ext_vector_type(8)));

__device__ __forceinline__ unsigned short f2bf(float f) {
  unsigned int u = __float_as_uint(f);
  u += 0x7fffu + ((u >> 16) & 1u);   // RTE
  return (unsigned short)(u >> 16);
}
__device__ __forceinline__ float bf2f(unsigned short v) {
  return __uint_as_float((unsigned int)v << 16);
}

__device__ __forceinline__ void pack16(const float4 v0, const float4 v1,
                                       const float4 v2, const float4 v3,
                                       unsigned short* dst) {
  u16x8 p0 = {f2bf(v0.x), f2bf(v0.y), f2bf(v0.z), f2bf(v0.w),
              f2bf(v1.x), f2bf(v1.y), f2bf(v1.z), f2bf(v1.w)};
  u16x8 p1 = {f2bf(v2.x), f2bf(v2.y), f2bf(v2.z), f2bf(v2.w),
              f2bf(v3.x), f2bf(v3.y), f2bf(v3.z), f2bf(v3.w)};
  *(u16x8*)(dst)     = p0;
  *(u16x8*)(dst + 8) = p1;
}

// 256-wide exclusive scan helper (all 256 threads must call)
__device__ __forceinline__ int scan256_excl(int v, int buf[2][256], int t) {
  int cur = 0;
  buf[0][t] = v;
  __syncthreads();
  for (int off = 1; off < 256; off <<= 1) {
    int nxt = cur ^ 1;
    int s = buf[cur][t];
    if (t >= off) s += buf[cur][t - off];
    buf[nxt][t] = s;
    cur = nxt;
    __syncthreads();
  }
  return buf[cur][t] - v;   // exclusive; buf[cur][255] = total-inclusive
}

// ---------------------------------------------------------------------------
// K1: h = bf16(relu(x @ proj_w^T + proj_b))   [50000,1024] x [128,1024]^T
// ---------------------------------------------------------------------------
__global__ __launch_bounds__(256) void k_proj(const float* __restrict__ x,
                                              const float* __restrict__ pw,
                                              const float* __restrict__ pb,
                                              unsigned short* __restrict__ h) {
  __shared__ unsigned short As[128 * 32];
  __shared__ unsigned short Bs[128 * 32];
  const int tid  = threadIdx.x;
  const int m0   = blockIdx.x * 128;
  const int wave = tid >> 6, lane = tid & 63;
  const int wm = (wave >> 1) * 64, wn = (wave & 1) * 64;
  const int srow = tid >> 1;
  const int scol = (tid & 1) * 16;
  const int fr = lane & 15, ko = (lane >> 4) * 8;

  f32x4 acc[4][4];
#pragma unroll
  for (int m = 0; m < 4; m++)
#pragma unroll
    for (int n = 0; n < 4; n++) acc[m][n] = (f32x4){0.f, 0.f, 0.f, 0.f};

  for (int k0 = 0; k0 < NODE_DIM; k0 += 32) {
    const int arow = m0 + srow;
    float4 a0, a1, a2, a3;
    if (arow < N_NODES) {
      const float4* p = (const float4*)(x + (size_t)arow * NODE_DIM + k0 + scol);
      a0 = p[0]; a1 = p[1]; a2 = p[2]; a3 = p[3];
    } else {
      a0 = a1 = a2 = a3 = make_float4(0.f, 0.f, 0.f, 0.f);
    }
    const float4* q = (const float4*)(pw + (size_t)srow * NODE_DIM + k0 + scol);
    float4 b0 = q[0], b1 = q[1], b2 = q[2], b3 = q[3];

    __syncthreads();
    pack16(a0, a1, a2, a3, &As[srow * 32 + scol]);
    pack16(b0, b1, b2, b3, &Bs[srow * 32 + scol]);
    __syncthreads();

    bf16x8 af[4], bfr[4];
#pragma unroll
    for (int m = 0; m < 4; m++)
      af[m] = *(const bf16x8*)&As[(wm + m * 16 + fr) * 32 + ko];
#pragma unroll
    for (int n = 0; n < 4; n++)
      bfr[n] = *(const bf16x8*)&Bs[(wn + n * 16 + fr) * 32 + ko];
#pragma unroll
    for (int m = 0; m < 4; m++)
#pragma unroll
      for (int n = 0; n < 4; n++)
        acc[m][n] = __builtin_amdgcn_mfma_f32_16x16x32_bf16(af[m], bfr[n], acc[m][n], 0, 0, 0);
  }

  const int cr = (lane >> 4) * 4, cc = lane & 15;
#pragma unroll
  for (int n = 0; n < 4; n++) {
    const int col = wn + n * 16 + cc;
    const float bias = pb[col];
#pragma unroll
    for (int m = 0; m < 4; m++) {
#pragma unroll
      for (int i = 0; i < 4; i++) {
        const int row = m0 + wm + m * 16 + cr + i;
        if (row < N_NODES) {
          float v = acc[m][n][i] + bias;
          h[(size_t)row * HID + col] = f2bf(v > 0.f ? v : 0.f);
        }
      }
    }
  }
}

// ---------------------------------------------------------------------------
// CSR build, atomic-free (global): hist -> scan -> scatter -> per-bucket CSR
// ---------------------------------------------------------------------------
__global__ __launch_bounds__(256) void k_hist(const int* __restrict__ ei,
                                              int* __restrict__ counts) {
  __shared__ int bins[NBUCK];
  int t = threadIdx.x;
  if (t < NBUCK) bins[t] = 0;
  __syncthreads();
  int base = blockIdx.x * SHARD;
  for (int i = t; i < SHARD; i += 256)
    atomicAdd(&bins[ei[N_EDGES + base + i] >> 8], 1);
  __syncthreads();
  if (t < NBUCK) counts[t * 256 + blockIdx.x] = bins[t];
}

// per-bucket scan over blocks -> per-(bucket,block) base + bucket totals
__global__ __launch_bounds__(256) void k_s1(const int* __restrict__ counts,
                                            int* __restrict__ basem,
                                            int* __restrict__ btot) {
  __shared__ int buf[2][256];
  int t = threadIdx.x, b = blockIdx.x;
  int v = counts[b * 256 + t];
  int excl = scan256_excl(v, buf, t);
  basem[b * 256 + t] = excl;
  if (t == 255) btot[b] = excl + v;
}

// scan bucket totals -> bucket starts; also zero the pool accumulator
__global__ __launch_bounds__(256) void k_s2(const int* __restrict__ btot,
                                            int* __restrict__ bstart,
                                            float* __restrict__ accum) {
  __shared__ int buf[2][256];
  int t = threadIdx.x;
  int v = (t < NBUCK) ? btot[t] : 0;
  int excl = scan256_excl(v, buf, t);
  if (t < NBUCK) bstart[t] = excl;
  if (t == 0) bstart[NBUCK] = N_EDGES;
  if (t < HID) accum[t] = 0.f;
}

// scatter edges into bucket-contiguous (src,dst) pairs via LDS cursors
__global__ __launch_bounds__(256) void k_scatter(const int* __restrict__ ei,
                                                 const int* __restrict__ basem,
                                                 const int* __restrict__ bstart,
                                                 int2* __restrict__ bs) {
  __shared__ int cur[NBUCK];
  int t = threadIdx.x;
  if (t < NBUCK) cur[t] = bstart[t] + basem[t * 256 + blockIdx.x];
  __syncthreads();
  int base = blockIdx.x * SHARD;
  for (int i = t; i < SHARD; i += 256) {
    int e = base + i;
    int src = ei[e];
    int dst = ei[N_EDGES + e];
    int pos = atomicAdd(&cur[dst >> 8], 1);
    bs[pos] = make_int2(src, dst);
  }
}

// per-bucket exact CSR: local histogram + scan + scatter (all LDS atomics)
__global__ __launch_bounds__(256) void k_bucket(const int* __restrict__ bstart,
                                                const int2* __restrict__ bs,
                                                int* __restrict__ nbr,
                                                int* __restrict__ offs,
                                                int* __restrict__ deg) {
  __shared__ int bins[256];
  __shared__ int buf[2][256];
  __shared__ int curs[256];
  int t = threadIdx.x, b = blockIdx.x;
  int s = bstart[b], e = bstart[b + 1];
  bins[t] = 0;
  __syncthreads();
  for (int i = s + t; i < e; i += 256)
    atomicAdd(&bins[bs[i].y & 255], 1);
  __syncthreads();
  int v = bins[t];
  int excl = scan256_excl(v, buf, t);
  int node = b * 256 + t;
  deg[node]  = v;
  offs[node] = s + excl;
  curs[t]    = s + excl;
  __syncthreads();
  for (int i = s + t; i < e; i += 256) {
    int2 p = bs[i];
    int pos = atomicAdd(&curs[p.y & 255], 1);
    nbr[pos] = p.x;
  }
}

// ---------------------------------------------------------------------------
// K3: gather + mean (bf16 h -> bf16 mn). One wave/node, 4 nbrs in flight,
// 16 lanes x 8 feats (16B) per neighbor.
// ---------------------------------------------------------------------------
__global__ __launch_bounds__(256) void k_gather(const unsigned short* __restrict__ h,
                                                const int* __restrict__ nbr,
                                                const int* __restrict__ offs,
                                                const int* __restrict__ deg,
                                                unsigned short* __restrict__ mn) {
  const int wave = threadIdx.x >> 6;
  const int lane = threadIdx.x & 63;
  const int node = blockIdx.x * 4 + wave;
  if (node >= N_NODES) return;
  const int g = lane >> 4, li = lane & 15;
  const int d  = deg[node];
  const int st = offs[node];
  float a[8] = {0.f, 0.f, 0.f, 0.f, 0.f, 0.f, 0.f, 0.f};
  for (int n = g; n < d; n += 4) {
    int sidx = nbr[st + n];
    u16x8 v = *(const u16x8*)(h + (size_t)sidx * HID + li * 8);
#pragma unroll
    for (int k = 0; k < 8; k++) a[k] += bf2f(v[k]);
  }
#pragma unroll
  for (int k = 0; k < 8; k++) {
    a[k] += __shfl_xor(a[k], 16);
    a[k] += __shfl_xor(a[k], 32);
  }
  if (g == 0) {
    float inv = 1.f / fmaxf((float)d, 1.f);
    u16x8 r;
#pragma unroll
    for (int k = 0; k < 8; k++) r[k] = f2bf(a[k] * inv);
    *(u16x8*)(mn + (size_t)node * HID + li * 8) = r;
  }
}

// ---------------------------------------------------------------------------
// K4: h2 = [mn | h] @ [lin_l_w | lin_r_w]^T + lin_l_b  (K=256 bf16 MFMA)
// written in place over mn (bf16). Row tiles disjoint across blocks.
// ---------------------------------------------------------------------------
__global__ __launch_bounds__(256) void k_sage(unsigned short* mn,
                                              const unsigned short* __restrict__ h,
                                              const float* __restrict__ wl,
                                              const float* __restrict__ wr,
                                              const float* __restrict__ lb) {
  __shared__ unsigned short As[128 * 32];
  __shared__ unsigned short Bs[128 * 32];
  const int tid  = threadIdx.x;
  const int m0   = blockIdx.x * 128;
  const int wave = tid >> 6, lane = tid & 63;
  const int wm = (wave >> 1) * 64, wn = (wave & 1) * 64;
  const int srow = tid >> 1;
  const int scol = (tid & 1) * 16;
  const int fr = lane & 15, ko = (lane >> 4) * 8;

  f32x4 acc[4][4];
#pragma unroll
  for (int m = 0; m < 4; m++)
#pragma unroll
    for (int n = 0; n < 4; n++) acc[m][n] = (f32x4){0.f, 0.f, 0.f, 0.f};

  for (int k0 = 0; k0 < 2 * HID; k0 += 32) {
    const unsigned short* baseA = (k0 < HID) ? mn : h;
    const float* baseB = (k0 < HID) ? wl : wr;
    const int kk = (k0 & (HID - 1)) + scol;
    const int arow = m0 + srow;
    u16x8 a0, a1;
    if (arow < N_NODES) {
      const u16x8* p = (const u16x8*)(baseA + (size_t)arow * HID + kk);
      a0 = p[0]; a1 = p[1];
    } else {
      a0 = (u16x8){0,0,0,0,0,0,0,0}; a1 = a0;
    }
    const float4* q = (const float4*)(baseB + (size_t)srow * HID + kk);
    float4 b0 = q[0], b1 = q[1], b2 = q[2], b3 = q[3];

    __syncthreads();
    *(u16x8*)&As[srow * 32 + scol]     = a0;
    *(u16x8*)&As[srow * 32 + scol + 8] = a1;
    pack16(b0, b1, b2, b3, &Bs[srow * 32 + scol]);
    __syncthreads();

    bf16x8 af[4], bfr[4];
#pragma unroll
    for (int m = 0; m < 4; m++)
      af[m] = *(const bf16x8*)&As[(wm + m * 16 + fr) * 32 + ko];
#pragma unroll
    for (int n = 0; n < 4; n++)
      bfr[n] = *(const bf16x8*)&Bs[(wn + n * 16 + fr) * 32 + ko];
#pragma unroll
    for (int m = 0; m < 4; m++)
#pragma unroll
      for (int n = 0; n < 4; n++)
        acc[m][n] = __builtin_amdgcn_mfma_f32_16x16x32_bf16(af[m], bfr[n], acc[m][n], 0, 0, 0);
  }

  const int cr = (lane >> 4) * 4, cc = lane & 15;
#pragma unroll
  for (int n = 0; n < 4; n++) {
    const int col = wn + n * 16 + cc;
    const float bias = lb[col];
#pragma unroll
    for (int m = 0; m < 4; m++) {
#pragma unroll
      for (int i = 0; i < 4; i++) {
        const int row = m0 + wm + m * 16 + cr + i;
        if (row < N_NODES)
          mn[(size_t)row * HID + col] = f2bf(acc[m][n][i] + bias);
      }
    }
  }
}

// ---------------------------------------------------------------------------
// K5: LayerNorm + ReLU + global mean-pool partials (bf16 input).
// Each lane owns feats (2l, 2l+1) via one 4B load.
// ---------------------------------------------------------------------------
__global__ __launch_bounds__(256) void k_ln_pool(const unsigned short* __restrict__ h2,
                                                 const float* __restrict__ lg,
                                                 const float* __restrict__ lbt,
                                                 float* __restrict__ accum) {
  const int wave = threadIdx.x >> 6;
  const int lane = threadIdx.x & 63;
  const int w = blockIdx.x * 4 + wave;
  const float g0 = lg[2 * lane], g1 = lg[2 * lane + 1];
  const float t0 = lbt[2 * lane], t1 = lbt[2 * lane + 1];
  float accx = 0.f, accy = 0.f;
  for (int i = w; i < N_NODES; i += 1024) {
    unsigned int pv = *(const unsigned int*)(h2 + (size_t)i * HID + 2 * lane);
    float v0 = bf2f((unsigned short)(pv & 0xffffu));
    float v1 = bf2f((unsigned short)(pv >> 16));
    float s = v0 + v1, ss = v0 * v0 + v1 * v1;
#pragma unroll
    for (int off = 32; off > 0; off >>= 1) {
      s  += __shfl_xor(s, off);
      ss += __shfl_xor(ss, off);
    }
    float mu  = s * (1.f / HID);
    float var = ss * (1.f / HID) - mu * mu;
    float r = rsqrtf(var + LN_EPS);
    float y0 = (v0 - mu) * r * g0 + t0;
    float y1 = (v1 - mu) * r * g1 + t1;
    accx += (y0 > 0.f ? y0 : 0.f);
    accy += (y1 > 0.f ? y1 : 0.f);
  }
  __shared__ float red[4][128];
  red[wave][2 * lane]     = accx;
  red[wave][2 * lane + 1] = accy;
  __syncthreads();
  if (wave == 0) {
    float a = red[0][2 * lane] + red[1][2 * lane] + red[2][2 * lane] + red[3][2 * lane];
    float b = red[0][2 * lane + 1] + red[1][2 * lane + 1] + red[2][2 * lane + 1] + red[3][2 * lane + 1];
    atomicAdd(&accum[2 * lane], a);
    atomicAdd(&accum[2 * lane + 1], b);
  }
}

// ---------------------------------------------------------------------------
// K6: out = (accum/N) @ out_w^T + out_b    (single block)
// ---------------------------------------------------------------------------
__global__ __launch_bounds__(128) void k_final(const float* __restrict__ accum,
                                               const float* __restrict__ ow,
                                               const float* __restrict__ ob,
                                               float* __restrict__ out) {
  __shared__ float gs[HID];
  int t = threadIdx.x;
  gs[t] = accum[t] * (1.f / N_NODES);
  __syncthreads();
  float s = ob[t];
  for (int k = 0; k < HID; k++) s += gs[k] * ow[t * HID + k];
  out[t] = s;
}

// ---------------------------------------------------------------------------
extern "C" void kernel_launch(void* const* d_in, const int* in_sizes, int n_in,
                              void* d_out, int out_size, void* d_ws, size_t ws_size,
                              hipStream_t stream) {
  const float* x   = (const float*)d_in[0];
  const int*   ei  = (const int*)d_in[1];
  const float* pw  = (const float*)d_in[2];
  const float* pb  = (const float*)d_in[3];
  const float* wl  = (const float*)d_in[4];
  const float* lb  = (const float*)d_in[5];
  const float* wr  = (const float*)d_in[6];
  const float* lg  = (const float*)d_in[7];
  const float* lbt = (const float*)d_in[8];
  const float* ow  = (const float*)d_in[9];
  const float* ob  = (const float*)d_in[10];
  float* out = (float*)d_out;

  // workspace carve (~45 MB)
  unsigned short* h  = (unsigned short*)d_ws;                 // PAD*128 bf16
  unsigned short* mn = h + (size_t)PAD_NODES * HID;           // PAD*128 bf16
  int2* bs   = (int2*)(mn + (size_t)PAD_NODES * HID);         // E pairs
  int* nbr   = (int*)(bs + N_EDGES);                          // E
  int* counts= nbr + N_EDGES;                                 // NBUCK*256
  int* basem = counts + NBUCK * 256;                          // NBUCK*256
  int* btot  = basem + NBUCK * 256;                           // NBUCK
  int* bstart= btot + 256;                                    // NBUCK+1 (pad)
  int* offs  = bstart + 256;                                  // PAD
  int* deg   = offs + PAD_NODES;                              // PAD
  float* accum = (float*)(deg + PAD_NODES);                   // 128

  const int MB = (N_NODES + 127) / 128;          // 391

  hipLaunchKernelGGL(k_proj,    dim3(MB),    dim3(256), 0, stream, x, pw, pb, h);
  hipLaunchKernelGGL(k_hist,    dim3(256),   dim3(256), 0, stream, ei, counts);
  hipLaunchKernelGGL(k_s1,      dim3(NBUCK), dim3(256), 0, stream, counts, basem, btot);
  hipLaunchKernelGGL(k_s2,      dim3(1),     dim3(256), 0, stream, btot, bstart, accum);
  hipLaunchKernelGGL(k_scatter, dim3(256),   dim3(256), 0, stream, ei, basem, bstart, bs);
  hipLaunchKernelGGL(k_bucket,  dim3(NBUCK), dim3(256), 0, stream, bstart, bs, nbr, offs, deg);
  hipLaunchKernelGGL(k_gather,  dim3((N_NODES + 3) / 4), dim3(256), 0, stream, h, nbr, offs, deg, mn);
  hipLaunchKernelGGL(k_sage,    dim3(MB),    dim3(256), 0, stream, mn, h, wl, wr, lb);
  hipLaunchKernelGGL(k_ln_pool, dim3(256),   dim3(256), 0, stream, mn, lg, lbt, accum);
  hipLaunchKernelGGL(k_final,   dim3(1),     dim3(128), 0, stream, accum, ow, ob, out);
}